// Round 1
// 155.157 us; speedup vs baseline: 1.0677x; 1.0677x over previous
//
#include <hip/hip_runtime.h>

// (B,P,C,H,W)=(256,10,32,8,8); Tm=19, Ta=10, hw=64. All I/O fp32.
// Horner: A_0=[F_0;1]; A_{p+1}=A_p*M_p+[F_{p+1};1] (p=0..8) -> A_9=[G;W]
// out[b,t,c,j] = (G[c,:].M_t[:,j]) / (W.M_t[:,j] + eps)
//
// v11 (from v10): kernel was latency-bound (VALUBusy 28%, HBM 25%, issue~19us
// of 68.6us). Three changes:
//  1. Phase 1: M_p staged in 16KB LDS; global float4 loads for M_{p+1} issued
//     BEFORE the inner loop (in flight across ~800cy of compute), ds_write
//     after the post-loop barrier (T14 async split). Inner loop is ds_read_b32
//     imm-offset, stride-1 (2-way aliasing = free), zero miss latency.
//  2. Phase 2 rebalanced: every wave does job t=wave (16x64), then t=8,9 as
//     8 quarter-jobs (4 rows x 64 cols), one per wave. Was 2 waves x 2 jobs.
//  3. XCD pairing: b=bid&255, h=bid>>8 -> sibling half-blocks differ by 256
//     (=0 mod 8 XCDs) -> share L2 for the batch's 150KB of sim.

#define EPSV 1e-6f

__device__ __forceinline__ float rdlane(float v, int k) {
    return __int_as_float(__builtin_amdgcn_readlane(__float_as_int(v), k));
}

__global__ __launch_bounds__(512, 4) void k_fused(
    const float* __restrict__ feats,   // (256,10,32,64)
    const float* __restrict__ sim,     // (256,19,64,64)
    float* __restrict__ out)           // (2560,32,64)
{
    __shared__ __attribute__((aligned(16))) float Mb[4096];   // 16KB: M_p stage
    __shared__ __attribute__((aligned(16))) float Gt[1280];   // 5KB: [G_half;W]^T

    const int tid  = threadIdx.x;
    const int lane = tid & 63;
    const int wave = tid >> 6;          // 0..7
    const int b    = blockIdx.x & 255;  // pair (b, b+256) -> same XCD
    const int h    = blockIdx.x >> 8;   // row-half of the batch

    const float* fb = feats + (size_t)b * 20480;   // 10*32*64
    const float* sb = sim   + (size_t)b * 77824;   // 19*64*64

    // ---- stage M_0 into LDS (coalesced float4, 512 thr x 32B) ----
    {
        const float4 s0 = *(const float4*)&sb[tid * 4];
        const float4 s1 = *(const float4*)&sb[2048 + tid * 4];
        *(float4*)&Mb[tid * 4]        = s0;
        *(float4*)&Mb[2048 + tid * 4] = s1;
    }

    // ---- phase 1: wave owns rows r0,r0+1 (wave 7 also W). ----
    const int r0 = 16 * h + 2 * wave;
    float a0 = fb[(r0 + 0) * 64 + lane];
    float a1 = fb[(r0 + 1) * 64 + lane];
    float aw = 1.0f;

    __syncthreads();                    // M_0 visible

    for (int p = 0; p < 9; ++p) {
        // prefetch M_{p+1} into regs: issued here, consumed after the loop;
        // cannot sink past the barrier -> stays in flight across the compute.
        float4 n0, n1;
        if (p < 8) {
            const float* __restrict__ Mn = sb + (p + 1) * 4096;
            n0 = *(const float4*)&Mn[tid * 4];
            n1 = *(const float4*)&Mn[2048 + tid * 4];
        }
        const float* __restrict__ F = fb + (p + 1) * 2048;
        const float f0 = F[(r0 + 0) * 64 + lane];
        const float f1 = F[(r0 + 1) * 64 + lane];

        float c0 = 0.f, c1 = 0.f, cw = 0.f;
        if (wave == 7) {                // wave-uniform branch
            #pragma unroll
            for (int k = 0; k < 64; ++k) {
                const float m = Mb[k * 64 + lane];   // ds_read_b32, imm offset
                c0 += rdlane(a0, k) * m;
                c1 += rdlane(a1, k) * m;
                cw += rdlane(aw, k) * m;
            }
        } else {
            #pragma unroll
            for (int k = 0; k < 64; ++k) {
                const float m = Mb[k * 64 + lane];
                c0 += rdlane(a0, k) * m;
                c1 += rdlane(a1, k) * m;
            }
        }
        a0 = c0 + f0; a1 = c1 + f1; aw = cw + 1.0f;

        if (p < 8) {
            __syncthreads();            // all waves done reading M_p
            *(float4*)&Mb[tid * 4]        = n0;   // vmcnt drained here (late)
            *(float4*)&Mb[2048 + tid * 4] = n1;
            __syncthreads();            // M_{p+1} visible
        }
    }

    // ---- handoff: half G + W -> LDS (k = lane, transposed one-time writes) ----
    Gt[lane * 20 + 2 * wave + 0] = a0;
    Gt[lane * 20 + 2 * wave + 1] = a1;
    if (wave == 7) Gt[lane * 20 + 16] = aw;
    __syncthreads();

    // ---- phase 2a: job t=wave, 16 rows x 64 cols on the owned half ----
    {
        const int rr = (lane >> 4) * 4;     // 0,4,8,12 (within the half)
        const int jj = (lane & 15) * 4;
        const int t  = wave;
        const float* __restrict__ Mt = sb + (9 + t) * 4096;

        float acc[16];
        #pragma unroll
        for (int i = 0; i < 16; ++i) acc[i] = 0.f;
        float wv0 = 0.f, wv1 = 0.f, wv2 = 0.f, wv3 = 0.f;

        #pragma unroll 16
        for (int k = 0; k < 64; ++k) {
            const float4 g  = *(const float4*)&Gt[k * 20 + rr];   // 4 rows @ k
            const float  wk = Gt[k * 20 + 16];                    // W[k]
            const float4 m  = *(const float4*)&Mt[k * 64 + jj];   // global b128
            wv0 += wk * m.x; wv1 += wk * m.y; wv2 += wk * m.z; wv3 += wk * m.w;
            acc[0]  += g.x*m.x; acc[1]  += g.x*m.y; acc[2]  += g.x*m.z; acc[3]  += g.x*m.w;
            acc[4]  += g.y*m.x; acc[5]  += g.y*m.y; acc[6]  += g.y*m.z; acc[7]  += g.y*m.w;
            acc[8]  += g.z*m.x; acc[9]  += g.z*m.y; acc[10] += g.z*m.z; acc[11] += g.z*m.w;
            acc[12] += g.w*m.x; acc[13] += g.w*m.y; acc[14] += g.w*m.z; acc[15] += g.w*m.w;
        }

        float4 rw;
        rw.x = 1.f / (wv0 + EPSV); rw.y = 1.f / (wv1 + EPSV);
        rw.z = 1.f / (wv2 + EPSV); rw.w = 1.f / (wv3 + EPSV);

        float* ob = out + ((size_t)b * 10 + t) * 2048;
        #pragma unroll
        for (int i = 0; i < 4; ++i) {
            float4 o;
            o.x = acc[i * 4 + 0] * rw.x;
            o.y = acc[i * 4 + 1] * rw.y;
            o.z = acc[i * 4 + 2] * rw.z;
            o.w = acc[i * 4 + 3] * rw.w;
            *(float4*)&ob[(16 * h + rr + i) * 64 + jj] = o;
        }
    }

    // ---- phase 2b: t=8,9 split into 8 quarter-jobs (4 rows x 64 cols) ----
    {
        const int t   = 8 + (wave >> 2);            // waves 0-3 -> t=8, 4-7 -> t=9
        const int row = (wave & 3) * 4 + (lane >> 4);  // 0..15 within the half
        const int jj  = (lane & 15) * 4;
        const float* __restrict__ Mt = sb + (9 + t) * 4096;

        float ac0 = 0.f, ac1 = 0.f, ac2 = 0.f, ac3 = 0.f;
        float wv0 = 0.f, wv1 = 0.f, wv2 = 0.f, wv3 = 0.f;

        #pragma unroll 16
        for (int k = 0; k < 64; ++k) {
            const float  g  = Gt[k * 20 + row];       // broadcast per 16-lane grp
            const float  wk = Gt[k * 20 + 16];
            const float4 m  = *(const float4*)&Mt[k * 64 + jj];
            ac0 += g * m.x;  ac1 += g * m.y;  ac2 += g * m.z;  ac3 += g * m.w;
            wv0 += wk * m.x; wv1 += wk * m.y; wv2 += wk * m.z; wv3 += wk * m.w;
        }

        float4 o;
        o.x = ac0 * (1.f / (wv0 + EPSV));
        o.y = ac1 * (1.f / (wv1 + EPSV));
        o.z = ac2 * (1.f / (wv2 + EPSV));
        o.w = ac3 * (1.f / (wv3 + EPSV));

        float* ob = out + ((size_t)b * 10 + t) * 2048;
        *(float4*)&ob[(16 * h + row) * 64 + jj] = o;
    }
}

extern "C" void kernel_launch(void* const* d_in, const int* in_sizes, int n_in,
                              void* d_out, int out_size, void* d_ws, size_t ws_size,
                              hipStream_t stream) {
    const float* feats = (const float*)d_in[0];
    const float* sim   = (const float*)d_in[1];
    k_fused<<<512, 512, 0, stream>>>(feats, sim, (float*)d_out);
}

// Round 2
// 149.538 us; speedup vs baseline: 1.1078x; 1.0376x over previous
//
#include <hip/hip_runtime.h>

// (B,P,C,H,W)=(256,10,32,8,8); Tm=19, Ta=10, hw=64. All I/O fp32.
// Horner: A_0=[F_0;1]; A_{p+1}=A_p*M_p+[F_{p+1};1] (p=0..8) -> A_9=[G;W]
// out[b,t,c,j] = (G[c,:].M_t[:,j]) / (W.M_t[:,j] + eps)
//
// v12 (from v11): still latency-bound (VALUBusy 38%, HBM 19%). Changes:
//  1. __launch_bounds__(512,2) (was 4): grid is exactly 2 blocks/CU, the old
//     bound capped VGPRs at 64 (compiler: 44) and killed load pipelining.
//  2. Mb double-buffered (2x16KB): ONE barrier per p-step (was 2). Writer
//     never waits for readers; 17 barriers -> 10.
//  3. p=8 peeled; phase-2a's first 8 Mt float4 loads issued before its
//     compute (~800cy early) so phase 2 doesn't start cold.
//  Balanced phase 2 (1 job + 1 quarter-job per wave) and XCD pairing kept.

#define EPSV 1e-6f

__device__ __forceinline__ float rdlane(float v, int k) {
    return __int_as_float(__builtin_amdgcn_readlane(__float_as_int(v), k));
}

__global__ __launch_bounds__(512, 2) void k_fused(
    const float* __restrict__ feats,   // (256,10,32,64)
    const float* __restrict__ sim,     // (256,19,64,64)
    float* __restrict__ out)           // (2560,32,64)
{
    __shared__ __attribute__((aligned(16))) float Mb[2][4096];  // 32KB dbuf
    __shared__ __attribute__((aligned(16))) float Gt[1280];     // 5KB handoff

    const int tid  = threadIdx.x;
    const int lane = tid & 63;
    const int wave = tid >> 6;          // 0..7
    const int b    = blockIdx.x & 255;  // pair (b, b+256) -> same XCD
    const int h    = blockIdx.x >> 8;   // row-half of the batch

    const float* fb = feats + (size_t)b * 20480;   // 10*32*64
    const float* sb = sim   + (size_t)b * 77824;   // 19*64*64

    // ---- stage M_0 into Mb[0] ----
    {
        const float4 s0 = *(const float4*)&sb[tid * 4];
        const float4 s1 = *(const float4*)&sb[2048 + tid * 4];
        *(float4*)&Mb[0][tid * 4]        = s0;
        *(float4*)&Mb[0][2048 + tid * 4] = s1;
    }

    // ---- phase 1: wave owns rows r0,r0+1 (wave 7 also W). ----
    const int r0 = 16 * h + 2 * wave;
    float a0 = fb[(r0 + 0) * 64 + lane];
    float a1 = fb[(r0 + 1) * 64 + lane];
    float aw = 1.0f;

    __syncthreads();                    // M_0 visible

    for (int p = 0; p < 8; ++p) {
        // prefetch M_{p+1}: in flight across the whole inner loop
        const float* __restrict__ Mn = sb + (p + 1) * 4096;
        const float4 n0 = *(const float4*)&Mn[tid * 4];
        const float4 n1 = *(const float4*)&Mn[2048 + tid * 4];
        const float* __restrict__ F = fb + (p + 1) * 2048;
        const float f0 = F[(r0 + 0) * 64 + lane];
        const float f1 = F[(r0 + 1) * 64 + lane];
        const float* __restrict__ Mc = Mb[p & 1];

        float c0 = 0.f, c1 = 0.f, cw = 0.f;
        if (wave == 7) {                // wave-uniform branch
            #pragma unroll
            for (int k = 0; k < 64; ++k) {
                const float m = Mc[k * 64 + lane];   // ds_read_b32, imm offset
                c0 += rdlane(a0, k) * m;
                c1 += rdlane(a1, k) * m;
                cw += rdlane(aw, k) * m;
            }
        } else {
            #pragma unroll
            for (int k = 0; k < 64; ++k) {
                const float m = Mc[k * 64 + lane];
                c0 += rdlane(a0, k) * m;
                c1 += rdlane(a1, k) * m;
            }
        }
        a0 = c0 + f0; a1 = c1 + f1; aw = cw + 1.0f;

        // write next buffer: no reader-wait needed (other buffer), 1 barrier
        float* Mw = Mb[(p + 1) & 1];
        *(float4*)&Mw[tid * 4]        = n0;
        *(float4*)&Mw[2048 + tid * 4] = n1;
        __syncthreads();
    }

    // ---- p=8 peeled, with phase-2a Mt prefetch issued up front ----
    const int rr = (lane >> 4) * 4;     // 0,4,8,12 (within the half)
    const int jj = (lane & 15) * 4;
    const float* __restrict__ Mt_a = sb + (9 + wave) * 4096;
    float4 pf[8];
    #pragma unroll
    for (int q = 0; q < 8; ++q) pf[q] = *(const float4*)&Mt_a[q * 64 + jj];

    {
        const float* __restrict__ F = fb + 9 * 2048;
        const float f0 = F[(r0 + 0) * 64 + lane];
        const float f1 = F[(r0 + 1) * 64 + lane];
        const float* __restrict__ Mc = Mb[0];      // M_8 landed in buf 0

        float c0 = 0.f, c1 = 0.f, cw = 0.f;
        if (wave == 7) {
            #pragma unroll
            for (int k = 0; k < 64; ++k) {
                const float m = Mc[k * 64 + lane];
                c0 += rdlane(a0, k) * m;
                c1 += rdlane(a1, k) * m;
                cw += rdlane(aw, k) * m;
            }
        } else {
            #pragma unroll
            for (int k = 0; k < 64; ++k) {
                const float m = Mc[k * 64 + lane];
                c0 += rdlane(a0, k) * m;
                c1 += rdlane(a1, k) * m;
            }
        }
        a0 = c0 + f0; a1 = c1 + f1; aw = cw + 1.0f;
    }

    // ---- handoff: half G + W -> LDS (k = lane, transposed writes) ----
    Gt[lane * 20 + 2 * wave + 0] = a0;
    Gt[lane * 20 + 2 * wave + 1] = a1;
    if (wave == 7) Gt[lane * 20 + 16] = aw;
    __syncthreads();                    // pf loads forced complete here too

    // ---- phase 2a: job t=wave, 16 rows x 64 cols on the owned half ----
    {
        const int t = wave;

        float acc[16];
        #pragma unroll
        for (int i = 0; i < 16; ++i) acc[i] = 0.f;
        float wv0 = 0.f, wv1 = 0.f, wv2 = 0.f, wv3 = 0.f;

        // k = 0..7 from the prefetch registers
        #pragma unroll
        for (int k = 0; k < 8; ++k) {
            const float4 g  = *(const float4*)&Gt[k * 20 + rr];
            const float  wk = Gt[k * 20 + 16];
            const float4 m  = pf[k];
            wv0 += wk * m.x; wv1 += wk * m.y; wv2 += wk * m.z; wv3 += wk * m.w;
            acc[0]  += g.x*m.x; acc[1]  += g.x*m.y; acc[2]  += g.x*m.z; acc[3]  += g.x*m.w;
            acc[4]  += g.y*m.x; acc[5]  += g.y*m.y; acc[6]  += g.y*m.z; acc[7]  += g.y*m.w;
            acc[8]  += g.z*m.x; acc[9]  += g.z*m.y; acc[10] += g.z*m.z; acc[11] += g.z*m.w;
            acc[12] += g.w*m.x; acc[13] += g.w*m.y; acc[14] += g.w*m.z; acc[15] += g.w*m.w;
        }
        // k = 8..63 from global (deep pipelining now that VGPRs allow)
        #pragma unroll 14
        for (int k = 8; k < 64; ++k) {
            const float4 g  = *(const float4*)&Gt[k * 20 + rr];
            const float  wk = Gt[k * 20 + 16];
            const float4 m  = *(const float4*)&Mt_a[k * 64 + jj];
            wv0 += wk * m.x; wv1 += wk * m.y; wv2 += wk * m.z; wv3 += wk * m.w;
            acc[0]  += g.x*m.x; acc[1]  += g.x*m.y; acc[2]  += g.x*m.z; acc[3]  += g.x*m.w;
            acc[4]  += g.y*m.x; acc[5]  += g.y*m.y; acc[6]  += g.y*m.z; acc[7]  += g.y*m.w;
            acc[8]  += g.z*m.x; acc[9]  += g.z*m.y; acc[10] += g.z*m.z; acc[11] += g.z*m.w;
            acc[12] += g.w*m.x; acc[13] += g.w*m.y; acc[14] += g.w*m.z; acc[15] += g.w*m.w;
        }

        float4 rw;
        rw.x = 1.f / (wv0 + EPSV); rw.y = 1.f / (wv1 + EPSV);
        rw.z = 1.f / (wv2 + EPSV); rw.w = 1.f / (wv3 + EPSV);

        float* ob = out + ((size_t)b * 10 + t) * 2048;
        #pragma unroll
        for (int i = 0; i < 4; ++i) {
            float4 o;
            o.x = acc[i * 4 + 0] * rw.x;
            o.y = acc[i * 4 + 1] * rw.y;
            o.z = acc[i * 4 + 2] * rw.z;
            o.w = acc[i * 4 + 3] * rw.w;
            *(float4*)&ob[(16 * h + rr + i) * 64 + jj] = o;
        }
    }

    // ---- phase 2b: t=8,9 split into 8 quarter-jobs (4 rows x 64 cols) ----
    {
        const int t   = 8 + (wave >> 2);               // waves 0-3 -> t=8, 4-7 -> 9
        const int row = (wave & 3) * 4 + (lane >> 4);  // 0..15 within the half
        const float* __restrict__ Mt = sb + (9 + t) * 4096;

        float ac0 = 0.f, ac1 = 0.f, ac2 = 0.f, ac3 = 0.f;
        float wv0 = 0.f, wv1 = 0.f, wv2 = 0.f, wv3 = 0.f;

        #pragma unroll 16
        for (int k = 0; k < 64; ++k) {
            const float  g  = Gt[k * 20 + row];        // 16-lane broadcast
            const float  wk = Gt[k * 20 + 16];
            const float4 m  = *(const float4*)&Mt[k * 64 + jj];
            ac0 += g * m.x;  ac1 += g * m.y;  ac2 += g * m.z;  ac3 += g * m.w;
            wv0 += wk * m.x; wv1 += wk * m.y; wv2 += wk * m.z; wv3 += wk * m.w;
        }

        float4 o;
        o.x = ac0 * (1.f / (wv0 + EPSV));
        o.y = ac1 * (1.f / (wv1 + EPSV));
        o.z = ac2 * (1.f / (wv2 + EPSV));
        o.w = ac3 * (1.f / (wv3 + EPSV));

        float* ob = out + ((size_t)b * 10 + t) * 2048;
        *(float4*)&ob[(16 * h + row) * 64 + jj] = o;
    }
}

extern "C" void kernel_launch(void* const* d_in, const int* in_sizes, int n_in,
                              void* d_out, int out_size, void* d_ws, size_t ws_size,
                              hipStream_t stream) {
    const float* feats = (const float*)d_in[0];
    const float* sim   = (const float*)d_in[1];
    k_fused<<<512, 512, 0, stream>>>(feats, sim, (float*)d_out);
}